// Round 1
// baseline (240.465 us; speedup 1.0000x reference)
//
#include <hip/hip_runtime.h>

#define L_N 4
#define C_ 128
#define S_ 81
#define TBS_ 128
#define ROWS_ (TBS_*S_)   // 10368
#define NQKV_ 384
#define EPS_ 1e-5f

typedef __bf16 bf;
typedef __attribute__((ext_vector_type(4))) __bf16 bf16x4;
typedef __attribute__((ext_vector_type(8))) __bf16 bf16x8;
typedef __attribute__((ext_vector_type(4))) float f32x4;

__device__ __forceinline__ float fast_exp2(float x) {
#if __has_builtin(__builtin_amdgcn_exp2f)
  return __builtin_amdgcn_exp2f(x);
#else
  return exp2f(x);
#endif
}
__device__ __forceinline__ float fast_rcp(float x) {
#if __has_builtin(__builtin_amdgcn_rcpf)
  return __builtin_amdgcn_rcpf(x);
#else
  return 1.0f / x;
#endif
}

// h[p][c] = x[p][0]*in_w[0][c] + x[p][1]*in_w[1][c] + in_b[c]
__global__ __launch_bounds__(256) void k_prep_h(const float* __restrict__ x,
                                                const float* __restrict__ in_w,
                                                const float* __restrict__ in_b,
                                                float* __restrict__ h) {
  int i = blockIdx.x * 256 + threadIdx.x;   // < ROWS_*C_
  int c = i & (C_ - 1);
  int p = i >> 7;
  h[i] = x[p * 2 + 0] * in_w[c] + x[p * 2 + 1] * in_w[C_ + c] + in_b[c];
}

// Swizzle qkv_w / full_w (fp32 [L][K][N]) into bf16 MFMA B-fragment order:
// element index = ((layer*T + t)*4 + s)*512 + lane*8 + j,
// value = W[layer][s*32 + (lane>>4)*8 + j][t*16 + (lane&15)]
__global__ __launch_bounds__(256) void k_prep_w(const float* __restrict__ qkv_w,
                                                const float* __restrict__ full_w,
                                                bf* __restrict__ wq, bf* __restrict__ wf) {
  int e = blockIdx.x * 256 + threadIdx.x;   // < 262144
  if (e < 196608) {
    int j = e & 7, l = (e >> 3) & 63, s = (e >> 9) & 3;
    int lt = e >> 11;            // layer*24 + t
    int t = lt % 24, layer = lt / 24;
    int k = s * 32 + ((l >> 4) << 3) + j;
    int n = t * 16 + (l & 15);
    wq[e] = (bf)qkv_w[(layer * C_ + k) * NQKV_ + n];
  } else {
    int e2 = e - 196608;
    int j = e2 & 7, l = (e2 >> 3) & 63, s = (e2 >> 9) & 3;
    int t = (e2 >> 11) & 7, layer = e2 >> 14;
    int k = s * 32 + ((l >> 4) << 3) + j;
    int n = t * 16 + (l & 15);
    wf[e2] = (bf)full_w[(layer * C_ + k) * C_ + n];
  }
}

// LayerNorm + qkv GEMM. 324 blocks x 256 threads; block = 32 rows.
__global__ __launch_bounds__(256) void k_lnqkv(const float* __restrict__ h,
                                               const float* __restrict__ ln_g,
                                               const float* __restrict__ ln_b,
                                               const bf* __restrict__ wq,
                                               const float* __restrict__ qkv_b,
                                               float* __restrict__ q, float* __restrict__ k,
                                               float* __restrict__ v, int layer) {
  __shared__ bf aFrag[2 * 4 * 64 * 8];   // A-fragment order: ((rg*4+s)*64+lane)*8+j
  int tid = threadIdx.x;
  int r0 = blockIdx.x * 32;

  // ---- stage 1: LN of 32 rows -> bf16 fragments in LDS ----
  int row = tid >> 3, g8 = tid & 7;
  const float* hrow = h + (size_t)(r0 + row) * C_;
  float vals[16];
  float sum = 0.f, ssq = 0.f;
#pragma unroll
  for (int it = 0; it < 4; ++it) {
    float4 f = *(const float4*)(hrow + g8 * 4 + it * 32);
    vals[it * 4 + 0] = f.x; vals[it * 4 + 1] = f.y;
    vals[it * 4 + 2] = f.z; vals[it * 4 + 3] = f.w;
    sum += f.x + f.y + f.z + f.w;
    ssq += f.x * f.x + f.y * f.y + f.z * f.z + f.w * f.w;
  }
#pragma unroll
  for (int off = 1; off < 8; off <<= 1) {
    sum += __shfl_xor(sum, off);
    ssq += __shfl_xor(ssq, off);
  }
  float mu = sum * (1.f / C_);
  float rs = rsqrtf(ssq * (1.f / C_) - mu * mu + EPS_);

  const float* lg = ln_g + layer * C_;
  const float* lb = ln_b + layer * C_;
  int rg = row >> 4, m = row & 15;
  int lgp = g8 >> 1, j0 = (g8 & 1) * 4;
#pragma unroll
  for (int it = 0; it < 4; ++it) {
    int c0 = g8 * 4 + it * 32;
    float4 gg = *(const float4*)(lg + c0);
    float4 bb = *(const float4*)(lb + c0);
    bf16x4 nv;
    nv[0] = (bf)((vals[it * 4 + 0] - mu) * rs * gg.x + bb.x);
    nv[1] = (bf)((vals[it * 4 + 1] - mu) * rs * gg.y + bb.y);
    nv[2] = (bf)((vals[it * 4 + 2] - mu) * rs * gg.z + bb.z);
    nv[3] = (bf)((vals[it * 4 + 3] - mu) * rs * gg.w + bb.w);
    *(bf16x4*)(aFrag + (((rg * 4 + it) * 64 + (lgp * 16 + m)) << 3) + j0) = nv;
  }
  __syncthreads();

  // ---- stage 2: GEMM [32 x 128] @ [128 x 384] ----
  int wave = tid >> 6, lane = tid & 63, l15 = lane & 15;
  const bf* wqL = wq + (size_t)layer * 24 * 4 * 64 * 8;
  f32x4 acc[2][6] = {};
#pragma unroll
  for (int s = 0; s < 4; ++s) {
    bf16x8 a0 = *(const bf16x8*)(aFrag + (((0 * 4 + s) * 64 + lane) << 3));
    bf16x8 a1 = *(const bf16x8*)(aFrag + (((1 * 4 + s) * 64 + lane) << 3));
#pragma unroll
    for (int tt = 0; tt < 6; ++tt) {
      int t = wave * 6 + tt;
      bf16x8 bfr = *(const bf16x8*)(wqL + (((t * 4 + s) * 64 + lane) << 3));
      acc[0][tt] = __builtin_amdgcn_mfma_f32_16x16x32_bf16(a0, bfr, acc[0][tt], 0, 0, 0);
      acc[1][tt] = __builtin_amdgcn_mfma_f32_16x16x32_bf16(a1, bfr, acc[1][tt], 0, 0, 0);
    }
  }

  const float* qb = qkv_b + layer * NQKV_;
#pragma unroll
  for (int tt = 0; tt < 6; ++tt) {
    int t = wave * 6 + tt;
    int col = t * 16 + l15;
    float bias = qb[col];
    float* dst; int cc;
    if (t < 8)       { dst = q; cc = col; }
    else if (t < 16) { dst = k; cc = col - 128; }
    else             { dst = v; cc = col - 256; }
#pragma unroll
    for (int rgi = 0; rgi < 2; ++rgi) {
#pragma unroll
      for (int r = 0; r < 4; ++r) {
        int R = r0 + rgi * 16 + ((lane >> 4) << 2) + r;
        dst[(size_t)R * C_ + cc] = acc[rgi][tt][r] + bias;
      }
    }
  }
}

// per-channel attention. 512 blocks (b x 4 channel-groups) x 256 threads.
__global__ __launch_bounds__(256) void k_attn(const float* __restrict__ q,
                                              const float* __restrict__ k,
                                              const float* __restrict__ v,
                                              bf* __restrict__ att) {
  __shared__ float2 kv[S_ * 32];
  __shared__ float redmax[8 * 32];
  __shared__ float redmin[8 * 32];
  int b = blockIdx.x >> 2;
  int c0 = (blockIdx.x & 3) * 32;
  int tid = threadIdx.x;
  const float* kb = k + (size_t)b * S_ * C_ + c0;
  const float* vb = v + (size_t)b * S_ * C_ + c0;
  for (int idx = tid; idx < S_ * 32; idx += 256) {
    int s = idx >> 5, c = idx & 31;
    kv[idx] = make_float2(kb[s * C_ + c], vb[s * C_ + c]);
  }
  __syncthreads();
  int c = tid & 31, qs = tid >> 5;
  float mx = -1e30f, mn = 1e30f;
  for (int s = qs; s < S_; s += 8) {
    float kk = kv[s * 32 + c].x;
    mx = fmaxf(mx, kk); mn = fminf(mn, kk);
  }
  redmax[qs * 32 + c] = mx; redmin[qs * 32 + c] = mn;
  __syncthreads();
  mx = -1e30f; mn = 1e30f;
#pragma unroll
  for (int i = 0; i < 8; ++i) {
    mx = fmaxf(mx, redmax[i * 32 + c]);
    mn = fminf(mn, redmin[i * 32 + c]);
  }
  const float log2e = 1.4426950408889634f;
  const float* qb = q + (size_t)b * S_ * C_ + c0;
  bf* ab = att + (size_t)b * S_ * C_ + c0;
  for (int qq = qs; qq < S_; qq += 8) {
    float x2 = qb[qq * C_ + c] * log2e;
    float m2 = fmaxf(x2 * mx, x2 * mn);   // exact max_k(x*k), no max pass
    float N0 = 0.f, N1 = 0.f, N2 = 0.f, D0 = 0.f, D1 = 0.f, D2 = 0.f;
    for (int kk = 0; kk < S_; kk += 3) {   // 81 = 27*3, 3 accumulation chains
      float2 a_ = kv[kk * 32 + c];
      float2 b_ = kv[kk * 32 + c + 32];
      float2 c_ = kv[kk * 32 + c + 64];
      float e0 = fast_exp2(__builtin_fmaf(x2, a_.x, -m2));
      float e1 = fast_exp2(__builtin_fmaf(x2, b_.x, -m2));
      float e2 = fast_exp2(__builtin_fmaf(x2, c_.x, -m2));
      D0 += e0; N0 = __builtin_fmaf(e0, a_.y, N0);
      D1 += e1; N1 = __builtin_fmaf(e1, b_.y, N1);
      D2 += e2; N2 = __builtin_fmaf(e2, c_.y, N2);
    }
    ab[qq * C_ + c] = (bf)((N0 + N1 + N2) * fast_rcp(D0 + D1 + D2));
  }
}

// att @ full_w + bias, relu, h += y. 324 blocks x 256 threads.
__global__ __launch_bounds__(256) void k_fullres(const bf* __restrict__ att,
                                                 const bf* __restrict__ wf,
                                                 const float* __restrict__ full_b,
                                                 float* __restrict__ h, int layer) {
  __shared__ bf aFrag[2 * 4 * 64 * 8];
  int tid = threadIdx.x;
  int r0 = blockIdx.x * 32;
  int row = tid >> 3, g8 = tid & 7;
  const bf* arow = att + (size_t)(r0 + row) * C_;
  int rg = row >> 4, m = row & 15;
  int lgp = g8 >> 1, j0 = (g8 & 1) * 4;
#pragma unroll
  for (int it = 0; it < 4; ++it) {
    int c0 = g8 * 4 + it * 32;
    bf16x4 nv = *(const bf16x4*)(arow + c0);
    *(bf16x4*)(aFrag + (((rg * 4 + it) * 64 + (lgp * 16 + m)) << 3) + j0) = nv;
  }
  __syncthreads();

  int wave = tid >> 6, lane = tid & 63, l15 = lane & 15;
  const bf* wfL = wf + (size_t)layer * 8 * 4 * 64 * 8;
  f32x4 acc[2][2] = {};
#pragma unroll
  for (int s = 0; s < 4; ++s) {
    bf16x8 a0 = *(const bf16x8*)(aFrag + (((0 * 4 + s) * 64 + lane) << 3));
    bf16x8 a1 = *(const bf16x8*)(aFrag + (((1 * 4 + s) * 64 + lane) << 3));
#pragma unroll
    for (int tt = 0; tt < 2; ++tt) {
      int t = wave * 2 + tt;
      bf16x8 bfr = *(const bf16x8*)(wfL + (((t * 4 + s) * 64 + lane) << 3));
      acc[0][tt] = __builtin_amdgcn_mfma_f32_16x16x32_bf16(a0, bfr, acc[0][tt], 0, 0, 0);
      acc[1][tt] = __builtin_amdgcn_mfma_f32_16x16x32_bf16(a1, bfr, acc[1][tt], 0, 0, 0);
    }
  }
  const float* fb = full_b + layer * C_;
#pragma unroll
  for (int tt = 0; tt < 2; ++tt) {
    int col = (wave * 2 + tt) * 16 + l15;
    float bias = fb[col];
#pragma unroll
    for (int rgi = 0; rgi < 2; ++rgi) {
#pragma unroll
      for (int r = 0; r < 4; ++r) {
        int R = r0 + rgi * 16 + ((lane >> 4) << 2) + r;
        size_t idx = (size_t)R * C_ + col;
        float y = fmaxf(acc[rgi][tt][r] + bias, 0.f);
        h[idx] += y;
      }
    }
  }
}

// out = h @ out_w + out_b. 324 blocks x 256 threads (8 threads/row).
__global__ __launch_bounds__(256) void k_out(const float* __restrict__ h,
                                             const float* __restrict__ out_w,
                                             const float* __restrict__ out_b,
                                             float* __restrict__ out) {
  int tid = threadIdx.x;
  int r0 = blockIdx.x * 32;
  int row = tid >> 3, g8 = tid & 7;
  const float* hrow = h + (size_t)(r0 + row) * C_;
  float o0 = 0.f, o1 = 0.f, o2 = 0.f, o3 = 0.f;
#pragma unroll
  for (int it = 0; it < 4; ++it) {
    int c0 = g8 * 4 + it * 32;
    float4 f = *(const float4*)(hrow + c0);
    float4 wA = *(const float4*)(out_w + (c0 + 0) * 4);
    float4 wB = *(const float4*)(out_w + (c0 + 1) * 4);
    float4 wC = *(const float4*)(out_w + (c0 + 2) * 4);
    float4 wD = *(const float4*)(out_w + (c0 + 3) * 4);
    o0 += f.x * wA.x + f.y * wB.x + f.z * wC.x + f.w * wD.x;
    o1 += f.x * wA.y + f.y * wB.y + f.z * wC.y + f.w * wD.y;
    o2 += f.x * wA.z + f.y * wB.z + f.z * wC.z + f.w * wD.z;
    o3 += f.x * wA.w + f.y * wB.w + f.z * wC.w + f.w * wD.w;
  }
#pragma unroll
  for (int off = 1; off < 8; off <<= 1) {
    o0 += __shfl_xor(o0, off); o1 += __shfl_xor(o1, off);
    o2 += __shfl_xor(o2, off); o3 += __shfl_xor(o3, off);
  }
  if (g8 == 0) {
    *(float4*)(out + (size_t)(r0 + row) * 4) = make_float4(o0, o1, o2, o3);
  }
}

extern "C" void kernel_launch(void* const* d_in, const int* in_sizes, int n_in,
                              void* d_out, int out_size, void* d_ws, size_t ws_size,
                              hipStream_t stream) {
  const float* x      = (const float*)d_in[0];
  const float* in_w   = (const float*)d_in[1];
  const float* in_b   = (const float*)d_in[2];
  const float* ln_g   = (const float*)d_in[3];
  const float* ln_b   = (const float*)d_in[4];
  const float* qkv_w  = (const float*)d_in[5];
  const float* qkv_b  = (const float*)d_in[6];
  const float* full_w = (const float*)d_in[7];
  const float* full_b = (const float*)d_in[8];
  const float* out_w  = (const float*)d_in[9];
  const float* out_b  = (const float*)d_in[10];

  float* h = (float*)d_ws;                       // 1327104 f
  float* q = h + 1327104;
  float* k = q + 1327104;
  float* v = k + 1327104;
  bf*  att = (bf*)(v + 1327104);                 // 1327104 bf16
  bf*  wq  = att + 1327104;                      // 196608 bf16
  bf*  wf  = wq + 196608;                        // 65536 bf16
  float* out = (float*)d_out;

  k_prep_h<<<5184, 256, 0, stream>>>(x, in_w, in_b, h);
  k_prep_w<<<1024, 256, 0, stream>>>(qkv_w, full_w, wq, wf);
  for (int layer = 0; layer < L_N; ++layer) {
    k_lnqkv<<<324, 256, 0, stream>>>(h, ln_g, ln_b, wq, qkv_b, q, k, v, layer);
    k_attn<<<512, 256, 0, stream>>>(q, k, v, att);
    k_fullres<<<324, 256, 0, stream>>>(att, wf, full_b, h, layer);
  }
  k_out<<<324, 256, 0, stream>>>(h, out_w, out_b, out);
}

// Round 2
// 235.023 us; speedup vs baseline: 1.0232x; 1.0232x over previous
//
#include <hip/hip_runtime.h>

#define NQKV_ 384
#define MAGIC_ 0x5CA1AB1E

typedef __bf16 bf;
typedef __attribute__((ext_vector_type(4))) __bf16 bf16x4;
typedef __attribute__((ext_vector_type(8))) __bf16 bf16x8;
typedef __attribute__((ext_vector_type(4))) float f32x4;

__device__ __forceinline__ float fast_exp2(float x) {
#if __has_builtin(__builtin_amdgcn_exp2f)
  return __builtin_amdgcn_exp2f(x);
#else
  return exp2f(x);
#endif
}
__device__ __forceinline__ float fast_rcp(float x) {
#if __has_builtin(__builtin_amdgcn_rcpf)
  return __builtin_amdgcn_rcpf(x);
#else
  return 1.0f / x;
#endif
}

// Swizzle qkv_w / full_w (fp32 [L][K][N]) into bf16 MFMA B-fragment order:
// element index = ((layer*T + t)*4 + s)*512 + lane*8 + j,
// value = W[layer][s*32 + (lane>>4)*8 + j][t*16 + (lane&15)]
__global__ __launch_bounds__(256) void k_prep_w(const float* __restrict__ qkv_w,
                                                const float* __restrict__ full_w,
                                                bf* __restrict__ wq, bf* __restrict__ wf) {
  int e = blockIdx.x * 256 + threadIdx.x;   // < 262144
  if (e < 196608) {
    int j = e & 7, l = (e >> 3) & 63, s = (e >> 9) & 3;
    int lt = e >> 11;            // layer*24 + t
    int t = lt % 24, layer = lt / 24;
    int k = s * 32 + ((l >> 4) << 3) + j;
    int n = t * 16 + (l & 15);
    wq[e] = (bf)qkv_w[(layer * 128 + k) * NQKV_ + n];
  } else {
    int e2 = e - 196608;
    int j = e2 & 7, l = (e2 >> 3) & 63, s = (e2 >> 9) & 3;
    int t = (e2 >> 11) & 7, layer = e2 >> 14;
    int k = s * 32 + ((l >> 4) << 3) + j;
    int n = t * 16 + (l & 15);
    wf[e2] = (bf)full_w[(layer * 128 + k) * 128 + n];
  }
}

// One block per (sequence b, channel-half). 256 blocks x 512 threads.
// Everything LDS-resident; pairwise att exchange through global + flags.
__global__ __launch_bounds__(512) void k_net(
    const float* __restrict__ x, const float* __restrict__ in_w,
    const float* __restrict__ in_b, const float* __restrict__ ln_g,
    const float* __restrict__ ln_b, const float* __restrict__ qkv_b,
    const float* __restrict__ full_b, const float* __restrict__ out_w,
    const float* __restrict__ out_b, const bf* __restrict__ wq,
    const bf* __restrict__ wf, bf* __restrict__ attg,
    int* __restrict__ flags, float* __restrict__ out) {
  __shared__ float h_s[81 * 128];        // 41472 B  residual stream (fp32, persistent)
  __shared__ bf afrag[96 * 128];         // 24576 B  A-fragments (LN out / att), bf16
  __shared__ float q_s[81 * 64];         // 20736 B  q*log2e for this half
  __shared__ float kvf[81 * 64 * 2];     // 41472 B  interleaved (k,v) fp32
  __shared__ bf att_s[96 * 128];         // 24576 B  full-channel att, bf16
  __shared__ float redmax[8 * 64];       // 2048 B
  __shared__ float redmin[8 * 64];       // 2048 B   total: 156928 B

  const int tid = threadIdx.x;
  const int bidx = blockIdx.x;
  const int b = bidx >> 1, half = bidx & 1, c0 = half * 64;
  const int wave = tid >> 6, lane = tid & 63, l15 = lane & 15, quad = lane >> 4;
  const float log2e = 1.4426950408889634f;

  // ---- h = x @ in_w + in_b (rows of this sequence) ----
  {
    const float* xb = x + (size_t)b * 162;
    for (int i = tid; i < 81 * 128; i += 512) {
      int p = i >> 7, c = i & 127;
      h_s[i] = xb[p * 2] * in_w[c] + xb[p * 2 + 1] * in_w[128 + c] + in_b[c];
    }
  }
  __syncthreads();

  for (int layer = 0; layer < 4; ++layer) {
    // ---- LayerNorm rows -> bf16 A-fragments ----
    {
      const float* lg = ln_g + layer * 128;
      const float* lb = ln_b + layer * 128;
      int rowl = tid >> 3, g8 = tid & 7;
      int lgp = g8 >> 1, j0 = (g8 & 1) * 4;
      for (int pass = 0; pass < 2; ++pass) {
        int row = pass * 64 + rowl;
        if (row < 81) {
          const float* hr = h_s + row * 128;
          float vals[16];
          float sum = 0.f, ssq = 0.f;
#pragma unroll
          for (int it = 0; it < 4; ++it) {
            float4 f = *(const float4*)(hr + g8 * 4 + it * 32);
            vals[it * 4 + 0] = f.x; vals[it * 4 + 1] = f.y;
            vals[it * 4 + 2] = f.z; vals[it * 4 + 3] = f.w;
            sum += f.x + f.y + f.z + f.w;
            ssq += f.x * f.x + f.y * f.y + f.z * f.z + f.w * f.w;
          }
#pragma unroll
          for (int off = 1; off < 8; off <<= 1) {
            sum += __shfl_xor(sum, off);
            ssq += __shfl_xor(ssq, off);
          }
          float mu = sum * (1.f / 128.f);
          float rs = rsqrtf(ssq * (1.f / 128.f) - mu * mu + 1e-5f);
          int mt = row >> 4, m = row & 15;
#pragma unroll
          for (int it = 0; it < 4; ++it) {
            int cc = g8 * 4 + it * 32;
            float4 gg = *(const float4*)(lg + cc);
            float4 bb = *(const float4*)(lb + cc);
            bf16x4 nv;
            nv[0] = (bf)((vals[it * 4 + 0] - mu) * rs * gg.x + bb.x);
            nv[1] = (bf)((vals[it * 4 + 1] - mu) * rs * gg.y + bb.y);
            nv[2] = (bf)((vals[it * 4 + 2] - mu) * rs * gg.z + bb.z);
            nv[3] = (bf)((vals[it * 4 + 3] - mu) * rs * gg.w + bb.w);
            *(bf16x4*)(afrag + (((mt * 4 + it) * 64 + (lgp * 16 + m)) << 3) + j0) = nv;
          }
        }
      }
    }
    __syncthreads();

    // ---- qkv GEMM (half): [96x128] @ [128x192], 72 tiles / 8 waves ----
    {
      const bf* wqL = wq + (size_t)layer * 24 * 2048;
      f32x4 acc[9] = {};
#pragma unroll
      for (int i = 0; i < 9; ++i) {
        int tau = wave + 8 * i;
        int Mt = tau / 12, Nt = tau % 12;
        int sec = Nt >> 2, off = Nt & 3;
        int tg = sec * 8 + half * 4 + off;
#pragma unroll
        for (int s = 0; s < 4; ++s) {
          bf16x8 a = *(const bf16x8*)(afrag + (((Mt * 4 + s) * 64 + lane) << 3));
          bf16x8 bb = *(const bf16x8*)(wqL + ((tg * 4 + s) * 512 + lane * 8));
          acc[i] = __builtin_amdgcn_mfma_f32_16x16x32_bf16(a, bb, acc[i], 0, 0, 0);
        }
      }
      const float* qb = qkv_b + layer * NQKV_;
#pragma unroll
      for (int i = 0; i < 9; ++i) {
        int tau = wave + 8 * i;
        int Mt = tau / 12, Nt = tau % 12;
        int sec = Nt >> 2, off = Nt & 3;
        int cl = off * 16 + l15;           // 0..63 within half-section
        float bias = qb[sec * 128 + c0 + cl];
        int Rb = Mt * 16 + quad * 4;
#pragma unroll
        for (int r = 0; r < 4; ++r) {
          int R = Rb + r;
          if (R < 81) {
            float vv = acc[i][r] + bias;
            if (sec == 0)      q_s[R * 64 + cl] = vv * log2e;
            else if (sec == 1) kvf[(R * 64 + cl) * 2] = vv;
            else               kvf[(R * 64 + cl) * 2 + 1] = vv;
          }
        }
      }
    }
    __syncthreads();

    // ---- per-channel attention for this half ----
    {
      int c = tid & 63, qs = tid >> 6;
      float mx = -1e30f, mn = 1e30f;
      for (int s = qs; s < 81; s += 8) {
        float kk = kvf[(s * 64 + c) * 2];
        mx = fmaxf(mx, kk); mn = fminf(mn, kk);
      }
      redmax[qs * 64 + c] = mx; redmin[qs * 64 + c] = mn;
      __syncthreads();
      mx = -1e30f; mn = 1e30f;
#pragma unroll
      for (int i = 0; i < 8; ++i) {
        mx = fmaxf(mx, redmax[i * 64 + c]);
        mn = fminf(mn, redmin[i * 64 + c]);
      }
      bf* ag = attg + ((size_t)(b * 2 + half) * 81) * 64;
      for (int qq = qs; qq < 81; qq += 8) {
        float x2 = q_s[qq * 64 + c];              // already *log2e
        float m2 = fmaxf(x2 * mx, x2 * mn);       // exact max_k(x*k)
        float N0 = 0.f, N1 = 0.f, N2 = 0.f, D0 = 0.f, D1 = 0.f, D2 = 0.f;
        for (int kk = 0; kk < 81; kk += 3) {
          float2 A = *(const float2*)(kvf + (kk * 64 + c) * 2);
          float2 B2 = *(const float2*)(kvf + (kk * 64 + c + 64) * 2);
          float2 C2 = *(const float2*)(kvf + (kk * 64 + c + 128) * 2);
          float e0 = fast_exp2(__builtin_fmaf(x2, A.x, -m2));
          float e1 = fast_exp2(__builtin_fmaf(x2, B2.x, -m2));
          float e2 = fast_exp2(__builtin_fmaf(x2, C2.x, -m2));
          D0 += e0; N0 = __builtin_fmaf(e0, A.y, N0);
          D1 += e1; N1 = __builtin_fmaf(e1, B2.y, N1);
          D2 += e2; N2 = __builtin_fmaf(e2, C2.y, N2);
        }
        bf ov = (bf)((N0 + N1 + N2) * fast_rcp(D0 + D1 + D2));
        att_s[qq * 128 + c0 + c] = ov;
        ag[qq * 64 + c] = ov;
      }
    }
    __syncthreads();

    // ---- exchange att halves with partner block (agent-scope) ----
    if (tid == 0) {
      __hip_atomic_store(&flags[bidx * 4 + layer], MAGIC_, __ATOMIC_RELEASE,
                         __HIP_MEMORY_SCOPE_AGENT);
      int peer = (bidx ^ 1) * 4 + layer;
      long guard = 0;
      while (__hip_atomic_load(&flags[peer], __ATOMIC_ACQUIRE,
                               __HIP_MEMORY_SCOPE_AGENT) != MAGIC_) {
        __builtin_amdgcn_s_sleep(2);
        if (++guard > (1L << 27)) break;   // safety valve vs. hang
      }
    }
    __syncthreads();
    {
      const bf* src = attg + ((size_t)(b * 2 + (1 - half)) * 81) * 64;
      int pc0 = 64 - c0;
      for (int i = tid; i < 81 * 64; i += 512) {
        int qq = i >> 6, c = i & 63;
        att_s[qq * 128 + pc0 + c] = src[i];
      }
    }
    __syncthreads();

    // ---- att -> A-fragments (pure LDS relayout) ----
    {
#pragma unroll
      for (int u = wave; u < 24; u += 8) {
        int mt = u >> 2, s = u & 3;
        bf16x8 val = *(const bf16x8*)(att_s + (mt * 16 + l15) * 128 + s * 32 + quad * 8);
        *(bf16x8*)(afrag + ((u * 64 + lane) << 3)) = val;
      }
    }
    __syncthreads();

    // ---- full GEMM + bias + relu + residual into h_s ----
    {
      const bf* wfL = wf + (size_t)layer * 8 * 2048;
      f32x4 acc[6] = {};
#pragma unroll
      for (int i = 0; i < 6; ++i) {
        int tau = wave + 8 * i;
        int Mt = tau >> 3, Nt = tau & 7;
#pragma unroll
        for (int s = 0; s < 4; ++s) {
          bf16x8 a = *(const bf16x8*)(afrag + (((Mt * 4 + s) * 64 + lane) << 3));
          bf16x8 bb = *(const bf16x8*)(wfL + ((Nt * 4 + s) * 512 + lane * 8));
          acc[i] = __builtin_amdgcn_mfma_f32_16x16x32_bf16(a, bb, acc[i], 0, 0, 0);
        }
      }
      const float* fb = full_b + layer * 128;
#pragma unroll
      for (int i = 0; i < 6; ++i) {
        int tau = wave + 8 * i;
        int Mt = tau >> 3, Nt = tau & 7;
        int col = Nt * 16 + l15;
        float bias = fb[col];
        int Rb = Mt * 16 + quad * 4;
#pragma unroll
        for (int r = 0; r < 4; ++r) {
          int R = Rb + r;
          if (R < 81) h_s[R * 128 + col] += fmaxf(acc[i][r] + bias, 0.f);
        }
      }
    }
    __syncthreads();
  }

  // ---- out = h @ out_w + out_b (half 0 writes) ----
  if (half == 0) {
    int rowl = tid >> 3, g8 = tid & 7;
    for (int pass = 0; pass < 2; ++pass) {
      int row = pass * 64 + rowl;
      if (row < 81) {
        const float* hr = h_s + row * 128;
        float o0 = 0.f, o1 = 0.f, o2 = 0.f, o3 = 0.f;
#pragma unroll
        for (int it = 0; it < 4; ++it) {
          int cc = g8 * 4 + it * 32;
          float4 f = *(const float4*)(hr + cc);
          float4 wA = *(const float4*)(out_w + (cc + 0) * 4);
          float4 wB = *(const float4*)(out_w + (cc + 1) * 4);
          float4 wC = *(const float4*)(out_w + (cc + 2) * 4);
          float4 wD = *(const float4*)(out_w + (cc + 3) * 4);
          o0 += f.x * wA.x + f.y * wB.x + f.z * wC.x + f.w * wD.x;
          o1 += f.x * wA.y + f.y * wB.y + f.z * wC.y + f.w * wD.y;
          o2 += f.x * wA.z + f.y * wB.z + f.z * wC.z + f.w * wD.z;
          o3 += f.x * wA.w + f.y * wB.w + f.z * wC.w + f.w * wD.w;
        }
#pragma unroll
        for (int off = 1; off < 8; off <<= 1) {
          o0 += __shfl_xor(o0, off); o1 += __shfl_xor(o1, off);
          o2 += __shfl_xor(o2, off); o3 += __shfl_xor(o3, off);
        }
        if (g8 == 0) {
          *(float4*)(out + ((size_t)b * 81 + row) * 4) =
              make_float4(o0 + out_b[0], o1 + out_b[1], o2 + out_b[2], o3 + out_b[3]);
        }
      }
    }
  }
}

extern "C" void kernel_launch(void* const* d_in, const int* in_sizes, int n_in,
                              void* d_out, int out_size, void* d_ws, size_t ws_size,
                              hipStream_t stream) {
  const float* x      = (const float*)d_in[0];
  const float* in_w   = (const float*)d_in[1];
  const float* in_b   = (const float*)d_in[2];
  const float* ln_g   = (const float*)d_in[3];
  const float* ln_b   = (const float*)d_in[4];
  const float* qkv_w  = (const float*)d_in[5];
  const float* qkv_b  = (const float*)d_in[6];
  const float* full_w = (const float*)d_in[7];
  const float* full_b = (const float*)d_in[8];
  const float* out_w  = (const float*)d_in[9];
  const float* out_b  = (const float*)d_in[10];

  bf* wq     = (bf*)d_ws;                  // 196608 bf16
  bf* wf     = wq + 196608;                // 65536 bf16
  bf* attg   = wf + 65536;                 // 128*2*81*64 = 1327104 bf16
  int* flags = (int*)(attg + 1327104);     // 256*4 ints (poisoned 0xAA each launch)
  float* out = (float*)d_out;

  k_prep_w<<<1024, 256, 0, stream>>>(qkv_w, full_w, wq, wf);
  k_net<<<256, 512, 0, stream>>>(x, in_w, in_b, ln_g, ln_b, qkv_b, full_b,
                                 out_w, out_b, wq, wf, attg, flags, out);
}

// Round 3
// 213.910 us; speedup vs baseline: 1.1241x; 1.0987x over previous
//
#include <hip/hip_runtime.h>

#define NQKV_ 384
#define MAGIC_ 0x5CA1AB1E

typedef __bf16 bf;
typedef __attribute__((ext_vector_type(4))) __bf16 bf16x4;
typedef __attribute__((ext_vector_type(8))) __bf16 bf16x8;
typedef __attribute__((ext_vector_type(4))) float f32x4;

__device__ __forceinline__ float fast_exp2(float x) {
#if __has_builtin(__builtin_amdgcn_exp2f)
  return __builtin_amdgcn_exp2f(x);
#else
  return exp2f(x);
#endif
}
__device__ __forceinline__ float fast_rcp(float x) {
#if __has_builtin(__builtin_amdgcn_rcpf)
  return __builtin_amdgcn_rcpf(x);
#else
  return 1.0f / x;
#endif
}

// Swizzle qkv_w / full_w (fp32 [L][K][N]) into bf16 MFMA B-fragment order:
// element index = ((layer*T + t)*4 + s)*512 + lane*8 + j,
// value = W[layer][s*32 + (lane>>4)*8 + j][t*16 + (lane&15)]
__global__ __launch_bounds__(256) void k_prep_w(const float* __restrict__ qkv_w,
                                                const float* __restrict__ full_w,
                                                bf* __restrict__ wq, bf* __restrict__ wf) {
  int e = blockIdx.x * 256 + threadIdx.x;   // < 262144
  if (e < 196608) {
    int j = e & 7, l = (e >> 3) & 63, s = (e >> 9) & 3;
    int lt = e >> 11;            // layer*24 + t
    int t = lt % 24, layer = lt / 24;
    int k = s * 32 + ((l >> 4) << 3) + j;
    int n = t * 16 + (l & 15);
    wq[e] = (bf)qkv_w[(layer * 128 + k) * NQKV_ + n];
  } else {
    int e2 = e - 196608;
    int j = e2 & 7, l = (e2 >> 3) & 63, s = (e2 >> 9) & 3;
    int t = (e2 >> 11) & 7, layer = e2 >> 14;
    int k = s * 32 + ((l >> 4) << 3) + j;
    int n = t * 16 + (l & 15);
    wf[e2] = (bf)full_w[(layer * 128 + k) * 128 + n];
  }
}

// One block per (sequence b, channel-half). 256 blocks x 1024 threads (16 waves).
// 136 KB LDS -> 1 block/CU, 16 waves/CU. Pairwise att exchange via global+flags.
__global__ __launch_bounds__(1024, 4) void k_net(
    const float* __restrict__ x, const float* __restrict__ in_w,
    const float* __restrict__ in_b, const float* __restrict__ ln_g,
    const float* __restrict__ ln_b, const float* __restrict__ qkv_b,
    const float* __restrict__ full_b, const float* __restrict__ out_w,
    const float* __restrict__ out_b, const bf* __restrict__ wq,
    const bf* __restrict__ wf, bf* __restrict__ attg,
    int* __restrict__ flags, float* __restrict__ out) {
  __shared__ float h_s[81 * 128];        // 41472 B  residual stream (fp32, persistent)
  __shared__ bf afrag[96 * 128];         // 24576 B  A-fragments (LN out / att), bf16
  __shared__ float q_s[81 * 64];         // 20736 B  q*log2e for this half
  __shared__ float kvf[81 * 64 * 2];     // 41472 B  interleaved (k,v) fp32
  __shared__ float redmax[16 * 64];      // 4096 B
  __shared__ float redmin[16 * 64];      // 4096 B   total: 136448 B

  const int tid = threadIdx.x;
  const int bidx = blockIdx.x;
  const int b = bidx >> 1, half = bidx & 1, c0 = half * 64;
  const int wave = tid >> 6, lane = tid & 63, l15 = lane & 15, quad = lane >> 4;
  const float log2e = 1.4426950408889634f;

  // ---- h = x @ in_w + in_b ----
  {
    const float* xb = x + (size_t)b * 162;
    for (int i = tid; i < 81 * 128; i += 1024) {
      int p = i >> 7, cc = i & 127;
      h_s[i] = xb[p * 2] * in_w[cc] + xb[p * 2 + 1] * in_w[128 + cc] + in_b[cc];
    }
  }
  __syncthreads();

  for (int layer = 0; layer < 4; ++layer) {
    // ---- LayerNorm rows -> bf16 A-fragments (single pass, 128 row-slots) ----
    {
      const float* lg = ln_g + layer * 128;
      const float* lb = ln_b + layer * 128;
      int row = tid >> 3, g8 = tid & 7;
      if (row < 81) {
        const float* hr = h_s + row * 128;
        float vals[16];
        float sum = 0.f, ssq = 0.f;
#pragma unroll
        for (int it = 0; it < 4; ++it) {
          float4 f = *(const float4*)(hr + g8 * 4 + it * 32);
          vals[it * 4 + 0] = f.x; vals[it * 4 + 1] = f.y;
          vals[it * 4 + 2] = f.z; vals[it * 4 + 3] = f.w;
          sum += f.x + f.y + f.z + f.w;
          ssq += f.x * f.x + f.y * f.y + f.z * f.z + f.w * f.w;
        }
#pragma unroll
        for (int off = 1; off < 8; off <<= 1) {
          sum += __shfl_xor(sum, off);
          ssq += __shfl_xor(ssq, off);
        }
        float mu = sum * (1.f / 128.f);
        float rs = rsqrtf(ssq * (1.f / 128.f) - mu * mu + 1e-5f);
        int mt = row >> 4, m = row & 15;
        int lgp = g8 >> 1, j0 = (g8 & 1) * 4;
#pragma unroll
        for (int it = 0; it < 4; ++it) {
          int cc = g8 * 4 + it * 32;
          float4 gg = *(const float4*)(lg + cc);
          float4 bb = *(const float4*)(lb + cc);
          bf16x4 nv;
          nv[0] = (bf)((vals[it * 4 + 0] - mu) * rs * gg.x + bb.x);
          nv[1] = (bf)((vals[it * 4 + 1] - mu) * rs * gg.y + bb.y);
          nv[2] = (bf)((vals[it * 4 + 2] - mu) * rs * gg.z + bb.z);
          nv[3] = (bf)((vals[it * 4 + 3] - mu) * rs * gg.w + bb.w);
          *(bf16x4*)(afrag + (((mt * 4 + it) * 64 + (lgp * 16 + m)) << 3) + j0) = nv;
        }
      }
    }
    __syncthreads();

    // ---- qkv GEMM (half): [96x128] @ [128x192], 72 tiles / 16 waves ----
    {
      const bf* wqL = wq + (size_t)layer * 24 * 2048;
      f32x4 acc[5] = {};
#pragma unroll
      for (int i = 0; i < 5; ++i) {
        int tau = wave + 16 * i;
        if (tau < 72) {
          int Mt = tau / 12, Nt = tau % 12;
          int sec = Nt >> 2, off = Nt & 3;
          int tg = sec * 8 + half * 4 + off;
#pragma unroll
          for (int s = 0; s < 4; ++s) {
            bf16x8 a = *(const bf16x8*)(afrag + (((Mt * 4 + s) * 64 + lane) << 3));
            bf16x8 bb = *(const bf16x8*)(wqL + ((tg * 4 + s) * 512 + lane * 8));
            acc[i] = __builtin_amdgcn_mfma_f32_16x16x32_bf16(a, bb, acc[i], 0, 0, 0);
          }
        }
      }
      const float* qb = qkv_b + layer * NQKV_;
#pragma unroll
      for (int i = 0; i < 5; ++i) {
        int tau = wave + 16 * i;
        if (tau < 72) {
          int Mt = tau / 12, Nt = tau % 12;
          int sec = Nt >> 2, off = Nt & 3;
          int cl = off * 16 + l15;           // 0..63 within half-section
          float bias = qb[sec * 128 + c0 + cl];
          int Rb = Mt * 16 + quad * 4;
#pragma unroll
          for (int r = 0; r < 4; ++r) {
            int R = Rb + r;
            if (R < 81) {
              float vv = acc[i][r] + bias;
              if (sec == 0)      q_s[R * 64 + cl] = vv * log2e;
              else if (sec == 1) kvf[(R * 64 + cl) * 2] = vv;
              else               kvf[(R * 64 + cl) * 2 + 1] = vv;
            }
          }
        }
      }
    }
    __syncthreads();

    // ---- per-channel attention for this half; output straight to afrag ----
    {
      int c = tid & 63, qs = tid >> 6;
      int cc = c0 + c;
      int sc = cc >> 5, qc = (cc >> 3) & 3, jc = cc & 7;
      float mx = -1e30f, mn = 1e30f;
      for (int s = qs; s < 81; s += 16) {
        float kk = kvf[(s * 64 + c) * 2];
        mx = fmaxf(mx, kk); mn = fminf(mn, kk);
      }
      redmax[qs * 64 + c] = mx; redmin[qs * 64 + c] = mn;
      __syncthreads();
      mx = -1e30f; mn = 1e30f;
#pragma unroll
      for (int i = 0; i < 16; ++i) {
        mx = fmaxf(mx, redmax[i * 64 + c]);
        mn = fminf(mn, redmin[i * 64 + c]);
      }
      bf* ag = attg + ((size_t)(b * 2 + half) * 81) * 64;

      // two paired passes: queries qs+32p and qs+32p+16 share each k,v load
#pragma unroll
      for (int p = 0; p < 2; ++p) {
        int q0 = qs + 32 * p, q1 = q0 + 16;
        float x0 = q_s[q0 * 64 + c], x1 = q_s[q1 * 64 + c];
        float m0 = fmaxf(x0 * mx, x0 * mn), m1 = fmaxf(x1 * mx, x1 * mn);
        float N00 = 0.f, N01 = 0.f, N02 = 0.f, D00 = 0.f, D01 = 0.f, D02 = 0.f;
        float N10 = 0.f, N11 = 0.f, N12 = 0.f, D10 = 0.f, D11 = 0.f, D12 = 0.f;
#pragma unroll 3
        for (int kk = 0; kk < 81; kk += 3) {
          float2 A = *(const float2*)(kvf + (kk * 64 + c) * 2);
          float2 B2 = *(const float2*)(kvf + ((kk + 1) * 64 + c) * 2);
          float2 C2 = *(const float2*)(kvf + ((kk + 2) * 64 + c) * 2);
          float e;
          e = fast_exp2(__builtin_fmaf(x0, A.x, -m0));  D00 += e; N00 = __builtin_fmaf(e, A.y, N00);
          e = fast_exp2(__builtin_fmaf(x1, A.x, -m1));  D10 += e; N10 = __builtin_fmaf(e, A.y, N10);
          e = fast_exp2(__builtin_fmaf(x0, B2.x, -m0)); D01 += e; N01 = __builtin_fmaf(e, B2.y, N01);
          e = fast_exp2(__builtin_fmaf(x1, B2.x, -m1)); D11 += e; N11 = __builtin_fmaf(e, B2.y, N11);
          e = fast_exp2(__builtin_fmaf(x0, C2.x, -m0)); D02 += e; N02 = __builtin_fmaf(e, C2.y, N02);
          e = fast_exp2(__builtin_fmaf(x1, C2.x, -m1)); D12 += e; N12 = __builtin_fmaf(e, C2.y, N12);
        }
        bf b0 = (bf)((N00 + N01 + N02) * fast_rcp(D00 + D01 + D02));
        bf b1 = (bf)((N10 + N11 + N12) * fast_rcp(D10 + D11 + D12));
        afrag[((((q0 >> 4) * 4 + sc) * 64 + qc * 16 + (q0 & 15)) << 3) + jc] = b0;
        ag[q0 * 64 + c] = b0;
        afrag[((((q1 >> 4) * 4 + sc) * 64 + qc * 16 + (q1 & 15)) << 3) + jc] = b1;
        ag[q1 * 64 + c] = b1;
      }
      // leftovers: qs+64 for all, plus q=80 for qs==0
      auto att_one = [&](int qq) {
        float x2 = q_s[qq * 64 + c];
        float m2 = fmaxf(x2 * mx, x2 * mn);
        float N0 = 0.f, N1 = 0.f, N2 = 0.f, D0 = 0.f, D1 = 0.f, D2 = 0.f;
#pragma unroll 3
        for (int kk = 0; kk < 81; kk += 3) {
          float2 A = *(const float2*)(kvf + (kk * 64 + c) * 2);
          float2 B2 = *(const float2*)(kvf + ((kk + 1) * 64 + c) * 2);
          float2 C2 = *(const float2*)(kvf + ((kk + 2) * 64 + c) * 2);
          float e0 = fast_exp2(__builtin_fmaf(x2, A.x, -m2));
          float e1 = fast_exp2(__builtin_fmaf(x2, B2.x, -m2));
          float e2 = fast_exp2(__builtin_fmaf(x2, C2.x, -m2));
          D0 += e0; N0 = __builtin_fmaf(e0, A.y, N0);
          D1 += e1; N1 = __builtin_fmaf(e1, B2.y, N1);
          D2 += e2; N2 = __builtin_fmaf(e2, C2.y, N2);
        }
        bf bv = (bf)((N0 + N1 + N2) * fast_rcp(D0 + D1 + D2));
        afrag[((((qq >> 4) * 4 + sc) * 64 + qc * 16 + (qq & 15)) << 3) + jc] = bv;
        ag[qq * 64 + c] = bv;
      };
      att_one(qs + 64);
      if (qs == 0) att_one(80);
    }
    __syncthreads();

    // ---- exchange att halves with partner block (agent-scope) ----
    if (tid == 0) {
      __hip_atomic_store(&flags[bidx * 4 + layer], MAGIC_, __ATOMIC_RELEASE,
                         __HIP_MEMORY_SCOPE_AGENT);
      int peer = (bidx ^ 1) * 4 + layer;
      long guard = 0;
      while (__hip_atomic_load(&flags[peer], __ATOMIC_ACQUIRE,
                               __HIP_MEMORY_SCOPE_AGENT) != MAGIC_) {
        __builtin_amdgcn_s_sleep(2);
        if (++guard > (1L << 27)) break;   // safety valve vs. hang
      }
    }
    __syncthreads();
    {
      const bf* src = attg + ((size_t)(b * 2 + (1 - half)) * 81) * 64;
      int pc0 = 64 - c0;
      for (int i = tid; i < 81 * 32; i += 1024) {
        int qq = i >> 5, cp = (i & 31) * 2;
        int ccp = pc0 + cp;                       // (ccp&7) is even
        ushort2 val = *(const ushort2*)((const unsigned short*)src + qq * 64 + cp);
        int idx = ((((qq >> 4) * 4 + (ccp >> 5)) * 64 + ((ccp >> 3) & 3) * 16 + (qq & 15)) << 3) + (ccp & 7);
        *(ushort2*)((unsigned short*)afrag + idx) = val;
      }
    }
    __syncthreads();

    // ---- full GEMM + bias + relu + residual into h_s: 48 tiles / 16 waves ----
    {
      const bf* wfL = wf + (size_t)layer * 8 * 2048;
      f32x4 acc[3] = {};
#pragma unroll
      for (int i = 0; i < 3; ++i) {
        int tau = wave + 16 * i;
        int Mt = tau >> 3, Nt = tau & 7;
#pragma unroll
        for (int s = 0; s < 4; ++s) {
          bf16x8 a = *(const bf16x8*)(afrag + (((Mt * 4 + s) * 64 + lane) << 3));
          bf16x8 bb = *(const bf16x8*)(wfL + ((Nt * 4 + s) * 512 + lane * 8));
          acc[i] = __builtin_amdgcn_mfma_f32_16x16x32_bf16(a, bb, acc[i], 0, 0, 0);
        }
      }
      const float* fb = full_b + layer * 128;
#pragma unroll
      for (int i = 0; i < 3; ++i) {
        int tau = wave + 16 * i;
        int Mt = tau >> 3, Nt = tau & 7;
        int col = Nt * 16 + l15;
        float bias = fb[col];
        int Rb = Mt * 16 + quad * 4;
#pragma unroll
        for (int r = 0; r < 4; ++r) {
          int R = Rb + r;
          if (R < 81) h_s[R * 128 + col] += fmaxf(acc[i][r] + bias, 0.f);
        }
      }
    }
    __syncthreads();
  }

  // ---- out = h @ out_w + out_b (half 0 writes) ----
  if (half == 0) {
    int row = tid >> 3, g8 = tid & 7;
    if (row < 81) {
      const float* hr = h_s + row * 128;
      float o0 = 0.f, o1 = 0.f, o2 = 0.f, o3 = 0.f;
#pragma unroll
      for (int it = 0; it < 4; ++it) {
        int cc = g8 * 4 + it * 32;
        float4 f = *(const float4*)(hr + cc);
        float4 wA = *(const float4*)(out_w + (cc + 0) * 4);
        float4 wB = *(const float4*)(out_w + (cc + 1) * 4);
        float4 wC = *(const float4*)(out_w + (cc + 2) * 4);
        float4 wD = *(const float4*)(out_w + (cc + 3) * 4);
        o0 += f.x * wA.x + f.y * wB.x + f.z * wC.x + f.w * wD.x;
        o1 += f.x * wA.y + f.y * wB.y + f.z * wC.y + f.w * wD.y;
        o2 += f.x * wA.z + f.y * wB.z + f.z * wC.z + f.w * wD.z;
        o3 += f.x * wA.w + f.y * wB.w + f.z * wC.w + f.w * wD.w;
      }
#pragma unroll
      for (int off = 1; off < 8; off <<= 1) {
        o0 += __shfl_xor(o0, off); o1 += __shfl_xor(o1, off);
        o2 += __shfl_xor(o2, off); o3 += __shfl_xor(o3, off);
      }
      if (g8 == 0) {
        *(float4*)(out + ((size_t)b * 81 + row) * 4) =
            make_float4(o0 + out_b[0], o1 + out_b[1], o2 + out_b[2], o3 + out_b[3]);
      }
    }
  }
}

extern "C" void kernel_launch(void* const* d_in, const int* in_sizes, int n_in,
                              void* d_out, int out_size, void* d_ws, size_t ws_size,
                              hipStream_t stream) {
  const float* x      = (const float*)d_in[0];
  const float* in_w   = (const float*)d_in[1];
  const float* in_b   = (const float*)d_in[2];
  const float* ln_g   = (const float*)d_in[3];
  const float* ln_b   = (const float*)d_in[4];
  const float* qkv_w  = (const float*)d_in[5];
  const float* qkv_b  = (const float*)d_in[6];
  const float* full_w = (const float*)d_in[7];
  const float* full_b = (const float*)d_in[8];
  const float* out_w  = (const float*)d_in[9];
  const float* out_b  = (const float*)d_in[10];

  bf* wq     = (bf*)d_ws;                  // 196608 bf16
  bf* wf     = wq + 196608;                // 65536 bf16
  bf* attg   = wf + 65536;                 // 128*2*81*64 = 1327104 bf16
  int* flags = (int*)(attg + 1327104);     // 256*4 ints (poisoned 0xAA each launch)
  float* out = (float*)d_out;

  k_prep_w<<<1024, 256, 0, stream>>>(qkv_w, full_w, wq, wf);
  k_net<<<256, 1024, 0, stream>>>(x, in_w, in_b, ln_g, ln_b, qkv_b, full_b,
                                  out_w, out_b, wq, wf, attg, flags, out);
}